// Round 7
// baseline (5418.327 us; speedup 1.0000x reference)
//
#include <hip/hip_runtime.h>
#include <stdint.h>

#define N_SITES 144
#define NHID    256
#define NSAMP   1024
#define MB      4          // samples per block
#define TPB     768        // one gate-column per thread; 12 waves = 3 waves/SIMD
#define PARTITIONABLE 1

__device__ __forceinline__ uint32_t rotl32(uint32_t v, uint32_t r) {
    return (v << r) | (v >> (32u - r));
}

// JAX threefry2x32: 20 rounds, key injections every 4
__device__ __forceinline__ void threefry(uint32_t k0, uint32_t k1,
                                         uint32_t x0, uint32_t x1,
                                         uint32_t& o0, uint32_t& o1) {
    uint32_t ks0 = k0, ks1 = k1, ks2 = k0 ^ k1 ^ 0x1BD11BDAu;
    x0 += ks0; x1 += ks1;
#define RG4(a,b,c,d) \
    x0 += x1; x1 = rotl32(x1,a); x1 ^= x0; \
    x0 += x1; x1 = rotl32(x1,b); x1 ^= x0; \
    x0 += x1; x1 = rotl32(x1,c); x1 ^= x0; \
    x0 += x1; x1 = rotl32(x1,d); x1 ^= x0;
    RG4(13,15,26,6)  x0 += ks1; x1 += ks2 + 1u;
    RG4(17,29,16,24) x0 += ks2; x1 += ks0 + 2u;
    RG4(13,15,26,6)  x0 += ks0; x1 += ks1 + 3u;
    RG4(17,29,16,24) x0 += ks1; x1 += ks2 + 4u;
    RG4(13,15,26,6)  x0 += ks2; x1 += ks0 + 5u;
#undef RG4
    o0 = x0; o1 = x1;
}

__device__ __forceinline__ float gumbel_from_bits(uint32_t bits) {
#pragma clang fp contract(off)
    const float TINY = 1.17549435e-38f;          // finfo(f32).tiny
    uint32_t fb = (bits >> 9) | 0x3f800000u;
    float u = __uint_as_float(fb) - 1.0f;        // [0,1)
    u = u * (1.0f - TINY) + TINY;                // matches JAX uniform()
    u = fmaxf(TINY, u);
    return -logf(-logf(u));
}

__global__ __launch_bounds__(TPB, 1)   // (TPB,1): VGPR cap 170 from block shape; do NOT raise min-waves (R3 spill)
void rnn_sample_kernel(const float* __restrict__ kern,   // [2,768]
                       const float* __restrict__ rec,    // [256,768]
                       const float* __restrict__ bias,   // [2,768]
                       const float* __restrict__ dw,     // [256,2]
                       const float* __restrict__ db,     // [2]
                       float* __restrict__ out)          // samples[1024*144] ++ logP[1024]
{
    const int t    = threadIdx.x;          // 0..767 == gate column index
    const int blk  = blockIdx.x;
    const int b0   = blk * MB;
    const int lane = t & 63;
    const int u    = t & 255;              // hidden-unit id for phase B/C
    const int m1   = t >> 8;               // first-pass sample id (0,1,2)

    __shared__ float4   hs4[NHID];          // h[k] packed over 4 samples (4 KB)
    __shared__ float    pacc[MB][TPB];      // phase-A partials, [sample][col] (12 KB)
    __shared__ uint32_t keyA[N_SITES], keyB[N_SITES];
    __shared__ float    glds[N_SITES][MB][2];  // precomputed gumbels (4.6 KB)
    __shared__ float    wred[MB][4][2];     // dense partials [sample][group][{a,b}]
    __shared__ int      sPrev[MB];

    // ---- VGPR-resident weights: every 4th row (k = 4g) of this thread's
    //      column, 64 registers. Cuts the per-step L1 weight return 25%
    //      (786->590 KB/CU/step, the measured dominant term) while keeping
    //      the streamed loads UNIFORMLY interleaved in the k chain (R4's
    //      contiguous-cache burst structure was the confirmed failure).
    //      Full unroll -> all wreg indices compile-time (no scratch). ----
    float wreg[64];
#pragma unroll
    for (int g = 0; g < 64; ++g) wreg[g] = rec[(size_t)(4 * g) * TPB + t];

    // ---- per-thread constants: unit-u gate triples (all 768 threads) ----
    const float kz0 = kern[u];        const float kr0 = kern[u + 256];  const float kn0 = kern[u + 512];
    const float kz1 = kern[768 + u];  const float kr1 = kern[768 + u + 256]; const float kn1 = kern[768 + u + 512];
    const float b0z = bias[u];        const float b0r = bias[u + 256];  const float b0n = bias[u + 512];
    const float b1z = bias[768 + u];  const float b1r = bias[768 + u + 256]; const float b1n = bias[768 + u + 512];
    const float dwa = dw[2 * u];      const float dwb = dw[2 * u + 1];
    const float dba = db[0];          const float dbb = db[1];
    float lgPr = 0.f;                                 // logP (threads 0..3)
    if (t < NHID) hs4[t] = make_float4(0.f, 0.f, 0.f, 0.f);
    if (t < MB) sPrev[t] = -1;
    if (t < N_SITES) {
        uint32_t o0, o1;
        threefry(0u, 42u, 0u, (uint32_t)t, o0, o1);   // foldlike split: counter = n
        keyA[t] = o0; keyB[t] = o1;
    }
    __syncthreads();

    // ---- gumbel precompute: data-independent, hoisted out of the step loop
    //      (same threefry inputs as the in-loop version -> bit-identical) ----
    if (t < N_SITES * MB) {
        const int n = t >> 2, m = t & 3;
        uint32_t o0a, o1a, o0b, o1b;
        const uint32_t fbase = 2u * (uint32_t)(b0 + m);
        threefry(keyA[n], keyB[n], 0u, fbase,      o0a, o1a);
        threefry(keyA[n], keyB[n], 0u, fbase + 1u, o0b, o1b);
        glds[n][m][0] = gumbel_from_bits(o0a ^ o1a);
        glds[n][m][1] = gumbel_from_bits(o0b ^ o1b);
    }
    __syncthreads();

    for (int n = 0; n < N_SITES; ++n) {
        // ---- phase A: one column per thread, single-accumulator ascending
        //      k=0..255 chain (bit-exact). k=4g from wreg (VGPR); k=4g+1..3
        //      streamed coalesced 4B/lane. Chain order unchanged. ----
        float a0 = 0.f, a1 = 0.f, a2 = 0.f, a3 = 0.f;
        {
            const float* rp = rec + t;
#pragma unroll
            for (int g = 0; g < 64; ++g) {
                const float w1 = rp[(size_t)(4 * g + 1) * TPB];
                const float w2 = rp[(size_t)(4 * g + 2) * TPB];
                const float w3 = rp[(size_t)(4 * g + 3) * TPB];
                float4 h4 = hs4[4 * g + 0];          // broadcast ds_read_b128
                a0 = fmaf(h4.x, wreg[g], a0);
                a1 = fmaf(h4.y, wreg[g], a1);
                a2 = fmaf(h4.z, wreg[g], a2);
                a3 = fmaf(h4.w, wreg[g], a3);
                h4 = hs4[4 * g + 1];
                a0 = fmaf(h4.x, w1, a0);
                a1 = fmaf(h4.y, w1, a1);
                a2 = fmaf(h4.z, w1, a2);
                a3 = fmaf(h4.w, w1, a3);
                h4 = hs4[4 * g + 2];
                a0 = fmaf(h4.x, w2, a0);
                a1 = fmaf(h4.y, w2, a1);
                a2 = fmaf(h4.z, w2, a2);
                a3 = fmaf(h4.w, w2, a3);
                h4 = hs4[4 * g + 3];
                a0 = fmaf(h4.x, w3, a0);
                a1 = fmaf(h4.y, w3, a1);
                a2 = fmaf(h4.z, w3, a2);
                a3 = fmaf(h4.w, w3, a3);
            }
        }
        pacc[0][t] = a0; pacc[1][t] = a1; pacc[2][t] = a2; pacc[3][t] = a3;
        __syncthreads();   // B1: pacc ready; all hs4 reads complete

        // ---- phases B+C spread over all 12 waves: 1024 (m,unit) gate tasks.
        //      Waves 0-3 handle m=0, 4-7 m=1, 8-11 m=2; second pass on waves
        //      0-3 handles m=3. Each task touches only component m of hs4[u];
        //      butterfly partials use identical lane positions/values as the
        //      old 4-wave version -> bit-exact. ----
#pragma unroll
        for (int pass = 0; pass < 2; ++pass) {
            const int m = (pass == 0) ? m1 : 3;
            if (pass == 1 && t >= NHID) break;
            float hnew;
            {
#pragma clang fp contract(off)
                const int sp = sPrev[m];
                float xz = (sp == 0) ? kz0 : ((sp == 1) ? kz1 : 0.f);
                float xr = (sp == 0) ? kr0 : ((sp == 1) ? kr1 : 0.f);
                float xh = (sp == 0) ? kn0 : ((sp == 1) ? kn1 : 0.f);
                xz = xz + b0z;  xr = xr + b0r;  xh = xh + b0n;
                const float hz = pacc[m][u]       + b1z;
                const float hr = pacc[m][u + 256] + b1r;
                const float hn = pacc[m][u + 512] + b1n;
                const float z = 1.0f / (1.0f + expf(-(xz + hz)));
                const float r = 1.0f / (1.0f + expf(-(xr + hr)));
                const float rhn = r * hn;
                const float hh = tanhf(xh + rhn);
                const float hold = ((const float*)&hs4[u])[m];   // component m only
                hnew = z * hold + (1.0f - z) * hh;
                ((float*)&hs4[u])[m] = hnew;                     // ds_write_b32
            }
            // dense logits partial (h @ dense_w): butterfly over 64 lanes,
            // group g = u>>6 reproduces the old per-wave partial exactly.
            float va = hnew * dwa;
            float vb = hnew * dwb;
#pragma unroll
            for (int off = 32; off > 0; off >>= 1) {
                va += __shfl_xor(va, off, 64);
                vb += __shfl_xor(vb, off, 64);
            }
            if (lane == 0) { wred[m][u >> 6][0] = va; wred[m][u >> 6][1] = vb; }
        }
        __syncthreads();   // B2: wred + hs4 ready

        // ---- phase D: logits + categorical + logP (4 threads, gumbels precomputed) ----
        if (t < MB) {
            const int m = t;
            // same summation order as the verified kernel: g0+g1+g2+g3, then bias
            float l0 = wred[m][0][0] + wred[m][1][0] + wred[m][2][0] + wred[m][3][0];
            float l1 = wred[m][0][1] + wred[m][1][1] + wred[m][2][1] + wred[m][3][1];
            const float g0 = glds[n][m][0];
            const float g1 = glds[n][m][1];
            {
#pragma clang fp contract(off)
                l0 = l0 + dba;
                l1 = l1 + dbb;
                const float mx = fmaxf(l0, l1);
                const float e0 = expf(l0 - mx), e1 = expf(l1 - mx);
                const float den = e0 + e1;
                const float lp0 = logf(1e-10f + e0 / den);
                const float lp1 = logf(1e-10f + e1 / den);
                const float v0 = g0 + lp0;
                const float v1 = g1 + lp1;
                const int s = (v1 > v0) ? 1 : 0;   // argmax, first-index tie-break
                sPrev[m] = s;
                lgPr = lgPr + (s ? lp1 : lp0);
                out[(size_t)(b0 + m) * N_SITES + n] = (float)s;
            }
        }
        // No third barrier (verified R4/R5/R6): phase D writes only
        // sPrev/out/lgPr(reg); next-step readers of sPrev are behind B1(n+1);
        // wred(n+1)/pacc(n+1) writes are behind B1(n+1) as well.
    }

    if (t < MB) out[(size_t)NSAMP * N_SITES + (b0 + t)] = lgPr;
}

extern "C" void kernel_launch(void* const* d_in, const int* in_sizes, int n_in,
                              void* d_out, int out_size, void* d_ws, size_t ws_size,
                              hipStream_t stream) {
    (void)in_sizes; (void)n_in; (void)d_ws; (void)ws_size; (void)out_size;
    const float* kern = (const float*)d_in[0];
    const float* rec  = (const float*)d_in[1];
    const float* bias = (const float*)d_in[2];
    const float* dwp  = (const float*)d_in[3];
    const float* dbp  = (const float*)d_in[4];
    float* out = (float*)d_out;
    rnn_sample_kernel<<<NSAMP / MB, TPB, 0, stream>>>(kern, rec, bias, dwp, dbp, out);
}

// Round 8
// 1323.914 us; speedup vs baseline: 4.0927x; 4.0927x over previous
//
#include <hip/hip_runtime.h>
#include <stdint.h>

#define N_SITES 144
#define NHID    256
#define NSAMP   1024
#define MB      4          // samples per block
#define TPB     768        // one gate-column per thread; 12 waves = 3 waves/SIMD
#define PARTITIONABLE 1

__device__ __forceinline__ uint32_t rotl32(uint32_t v, uint32_t r) {
    return (v << r) | (v >> (32u - r));
}

// JAX threefry2x32: 20 rounds, key injections every 4
__device__ __forceinline__ void threefry(uint32_t k0, uint32_t k1,
                                         uint32_t x0, uint32_t x1,
                                         uint32_t& o0, uint32_t& o1) {
    uint32_t ks0 = k0, ks1 = k1, ks2 = k0 ^ k1 ^ 0x1BD11BDAu;
    x0 += ks0; x1 += ks1;
#define RG4(a,b,c,d) \
    x0 += x1; x1 = rotl32(x1,a); x1 ^= x0; \
    x0 += x1; x1 = rotl32(x1,b); x1 ^= x0; \
    x0 += x1; x1 = rotl32(x1,c); x1 ^= x0; \
    x0 += x1; x1 = rotl32(x1,d); x1 ^= x0;
    RG4(13,15,26,6)  x0 += ks1; x1 += ks2 + 1u;
    RG4(17,29,16,24) x0 += ks2; x1 += ks0 + 2u;
    RG4(13,15,26,6)  x0 += ks0; x1 += ks1 + 3u;
    RG4(17,29,16,24) x0 += ks1; x1 += ks2 + 4u;
    RG4(13,15,26,6)  x0 += ks2; x1 += ks0 + 5u;
#undef RG4
    o0 = x0; o1 = x1;
}

__device__ __forceinline__ float gumbel_from_bits(uint32_t bits) {
#pragma clang fp contract(off)
    const float TINY = 1.17549435e-38f;          // finfo(f32).tiny
    uint32_t fb = (bits >> 9) | 0x3f800000u;
    float u = __uint_as_float(fb) - 1.0f;        // [0,1)
    u = u * (1.0f - TINY) + TINY;                // matches JAX uniform()
    u = fmaxf(TINY, u);
    return -logf(-logf(u));
}

// One-time prep: recQ[k/4][col][j] = rec[4*(k/4)+j][col]  (786 KB workspace).
// Pure copy -> bit-exact. Gives phase A 16 B/lane loads that are ALSO
// wave-coalesced (lane-adjacent threads 16 B apart; 1 KB contiguous per
// instruction). R5's column-contiguous layout had 16 B/lane but lanes 1 KB
// apart -> 64 lines/instr -> 4x slower memory path. This is the fix.
__global__ void repack_rec(const float* __restrict__ rec,
                           float* __restrict__ recQ) {
    const int col = blockIdx.x;           // 0..767
    const int k   = threadIdx.x;          // 0..255
    recQ[((size_t)(k >> 2) * TPB + col) * 4 + (k & 3)] = rec[(size_t)k * TPB + col];
}

template <bool QUAD>
__global__ __launch_bounds__(TPB, 1)
void rnn_sample_kernel(const float* __restrict__ kern,   // [2,768]
                       const float* __restrict__ rec,    // QUAD ? recQ[64][768][4] : rec[256][768]
                       const float* __restrict__ bias,   // [2,768]
                       const float* __restrict__ dw,     // [256,2]
                       const float* __restrict__ db,     // [2]
                       float* __restrict__ out)          // samples[1024*144] ++ logP[1024]
{
    const int t    = threadIdx.x;          // 0..767 == gate column index
    const int blk  = blockIdx.x;
    const int b0   = blk * MB;
    const int lane = t & 63;
    const int u    = t & 255;              // hidden-unit id for phase B/C
    const int m1   = t >> 8;               // first-pass sample id (0,1,2)

    __shared__ float4   hs4[NHID];          // h[k] packed over 4 samples (4 KB)
    __shared__ float    pacc[MB][TPB];      // phase-A partials, [sample][col] (12 KB)
    __shared__ uint32_t keyA[N_SITES], keyB[N_SITES];
    __shared__ float    glds[N_SITES][MB][2];  // precomputed gumbels (4.6 KB)
    __shared__ float    wred[MB][4][2];     // dense partials [sample][group][{a,b}]
    __shared__ int      sPrev[MB];

    // ---- per-thread constants: unit-u gate triples (all 768 threads) ----
    const float kz0 = kern[u];        const float kr0 = kern[u + 256];  const float kn0 = kern[u + 512];
    const float kz1 = kern[768 + u];  const float kr1 = kern[768 + u + 256]; const float kn1 = kern[768 + u + 512];
    const float b0z = bias[u];        const float b0r = bias[u + 256];  const float b0n = bias[u + 512];
    const float b1z = bias[768 + u];  const float b1r = bias[768 + u + 256]; const float b1n = bias[768 + u + 512];
    const float dwa = dw[2 * u];      const float dwb = dw[2 * u + 1];
    const float dba = db[0];          const float dbb = db[1];
    float lgPr = 0.f;                                 // logP (threads 0..3)
    if (t < NHID) hs4[t] = make_float4(0.f, 0.f, 0.f, 0.f);
    if (t < MB) sPrev[t] = -1;
    if (t < N_SITES) {
        uint32_t o0, o1;
        threefry(0u, 42u, 0u, (uint32_t)t, o0, o1);   // foldlike split: counter = n
        keyA[t] = o0; keyB[t] = o1;
    }
    __syncthreads();

    // ---- gumbel precompute: data-independent, hoisted out of the step loop
    //      (same threefry inputs as the in-loop version -> bit-identical) ----
    if (t < N_SITES * MB) {
        const int n = t >> 2, m = t & 3;
        uint32_t o0a, o1a, o0b, o1b;
        const uint32_t fbase = 2u * (uint32_t)(b0 + m);
        threefry(keyA[n], keyB[n], 0u, fbase,      o0a, o1a);
        threefry(keyA[n], keyB[n], 0u, fbase + 1u, o0b, o1b);
        glds[n][m][0] = gumbel_from_bits(o0a ^ o1a);
        glds[n][m][1] = gumbel_from_bits(o0b ^ o1b);
    }
    __syncthreads();

    for (int n = 0; n < N_SITES; ++n) {
        // ---- phase A: one column per thread, single-accumulator ascending
        //      k=0..255 chain (bit-exact). QUAD: one dwordx4 per 4 k's,
        //      coalesced AND deep-in-flight (8 KB/wave at unroll 8). ----
        float a0 = 0.f, a1 = 0.f, a2 = 0.f, a3 = 0.f;
        if (QUAD) {
            const float4* rq = reinterpret_cast<const float4*>(rec) + t;
#pragma unroll 8
            for (int g = 0; g < 64; ++g) {
                const float4 w = rq[(size_t)g * TPB];   // k = 4g..4g+3 of column t
                float4 h4 = hs4[4 * g + 0];             // broadcast ds_read_b128
                a0 = fmaf(h4.x, w.x, a0);
                a1 = fmaf(h4.y, w.x, a1);
                a2 = fmaf(h4.z, w.x, a2);
                a3 = fmaf(h4.w, w.x, a3);
                h4 = hs4[4 * g + 1];
                a0 = fmaf(h4.x, w.y, a0);
                a1 = fmaf(h4.y, w.y, a1);
                a2 = fmaf(h4.z, w.y, a2);
                a3 = fmaf(h4.w, w.y, a3);
                h4 = hs4[4 * g + 2];
                a0 = fmaf(h4.x, w.z, a0);
                a1 = fmaf(h4.y, w.z, a1);
                a2 = fmaf(h4.z, w.z, a2);
                a3 = fmaf(h4.w, w.z, a3);
                h4 = hs4[4 * g + 3];
                a0 = fmaf(h4.x, w.w, a0);
                a1 = fmaf(h4.y, w.w, a1);
                a2 = fmaf(h4.z, w.w, a2);
                a3 = fmaf(h4.w, w.w, a3);
            }
        } else {
            const float* rp = rec + t;
#pragma unroll 8
            for (int k = 0; k < NHID; ++k) {
                float4 h4 = hs4[k];          // broadcast ds_read_b128
                float w  = rp[0];
                rp += TPB;
                a0 = fmaf(h4.x, w, a0);
                a1 = fmaf(h4.y, w, a1);
                a2 = fmaf(h4.z, w, a2);
                a3 = fmaf(h4.w, w, a3);
            }
        }
        pacc[0][t] = a0; pacc[1][t] = a1; pacc[2][t] = a2; pacc[3][t] = a3;
        __syncthreads();   // B1: pacc ready; all hs4 reads complete

        // ---- phases B+C spread over all 12 waves: 1024 (m,unit) gate tasks.
        //      Waves 0-3 handle m=0, 4-7 m=1, 8-11 m=2; second pass on waves
        //      0-3 handles m=3. Each task touches only component m of hs4[u];
        //      butterfly partials use identical lane positions/values as the
        //      old 4-wave version -> bit-exact. (R6-verbatim, verified) ----
#pragma unroll
        for (int pass = 0; pass < 2; ++pass) {
            const int m = (pass == 0) ? m1 : 3;
            if (pass == 1 && t >= NHID) break;
            float hnew;
            {
#pragma clang fp contract(off)
                const int sp = sPrev[m];
                float xz = (sp == 0) ? kz0 : ((sp == 1) ? kz1 : 0.f);
                float xr = (sp == 0) ? kr0 : ((sp == 1) ? kr1 : 0.f);
                float xh = (sp == 0) ? kn0 : ((sp == 1) ? kn1 : 0.f);
                xz = xz + b0z;  xr = xr + b0r;  xh = xh + b0n;
                const float hz = pacc[m][u]       + b1z;
                const float hr = pacc[m][u + 256] + b1r;
                const float hn = pacc[m][u + 512] + b1n;
                const float z = 1.0f / (1.0f + expf(-(xz + hz)));
                const float r = 1.0f / (1.0f + expf(-(xr + hr)));
                const float rhn = r * hn;
                const float hh = tanhf(xh + rhn);
                const float hold = ((const float*)&hs4[u])[m];   // component m only
                hnew = z * hold + (1.0f - z) * hh;
                ((float*)&hs4[u])[m] = hnew;                     // ds_write_b32
            }
            // dense logits partial (h @ dense_w): butterfly over 64 lanes,
            // group g = u>>6 reproduces the old per-wave partial exactly.
            float va = hnew * dwa;
            float vb = hnew * dwb;
#pragma unroll
            for (int off = 32; off > 0; off >>= 1) {
                va += __shfl_xor(va, off, 64);
                vb += __shfl_xor(vb, off, 64);
            }
            if (lane == 0) { wred[m][u >> 6][0] = va; wred[m][u >> 6][1] = vb; }
        }
        __syncthreads();   // B2: wred + hs4 ready

        // ---- phase D: logits + categorical + logP (4 threads, gumbels precomputed) ----
        if (t < MB) {
            const int m = t;
            // same summation order as the verified kernel: g0+g1+g2+g3, then bias
            float l0 = wred[m][0][0] + wred[m][1][0] + wred[m][2][0] + wred[m][3][0];
            float l1 = wred[m][0][1] + wred[m][1][1] + wred[m][2][1] + wred[m][3][1];
            const float g0 = glds[n][m][0];
            const float g1 = glds[n][m][1];
            {
#pragma clang fp contract(off)
                l0 = l0 + dba;
                l1 = l1 + dbb;
                const float mx = fmaxf(l0, l1);
                const float e0 = expf(l0 - mx), e1 = expf(l1 - mx);
                const float den = e0 + e1;
                const float lp0 = logf(1e-10f + e0 / den);
                const float lp1 = logf(1e-10f + e1 / den);
                const float v0 = g0 + lp0;
                const float v1 = g1 + lp1;
                const int s = (v1 > v0) ? 1 : 0;   // argmax, first-index tie-break
                sPrev[m] = s;
                lgPr = lgPr + (s ? lp1 : lp0);
                out[(size_t)(b0 + m) * N_SITES + n] = (float)s;
            }
        }
        // No third barrier (verified R4-R6): phase D writes only
        // sPrev/out/lgPr(reg); next-step readers of sPrev are behind B1(n+1);
        // wred(n+1)/pacc(n+1) writes are behind B1(n+1) as well.
    }

    if (t < MB) out[(size_t)NSAMP * N_SITES + (b0 + t)] = lgPr;
}

extern "C" void kernel_launch(void* const* d_in, const int* in_sizes, int n_in,
                              void* d_out, int out_size, void* d_ws, size_t ws_size,
                              hipStream_t stream) {
    (void)in_sizes; (void)n_in; (void)out_size;
    const float* kern = (const float*)d_in[0];
    const float* rec  = (const float*)d_in[1];
    const float* bias = (const float*)d_in[2];
    const float* dwp  = (const float*)d_in[3];
    const float* dbp  = (const float*)d_in[4];
    float* out = (float*)d_out;

    const size_t needQ = sizeof(float) * (size_t)NHID * TPB;   // 786 KB
    if (d_ws != nullptr && ws_size >= needQ) {
        float* recQ = (float*)d_ws;
        repack_rec<<<TPB, NHID, 0, stream>>>(rec, recQ);
        rnn_sample_kernel<true><<<NSAMP / MB, TPB, 0, stream>>>(kern, recQ, bias, dwp, dbp, out);
    } else {
        rnn_sample_kernel<false><<<NSAMP / MB, TPB, 0, stream>>>(kern, rec, bias, dwp, dbp, out);
    }
}